// Round 7
// baseline (220.490 us; speedup 1.0000x reference)
//
#include <hip/hip_runtime.h>

// out[b,n,m] = cost_class + cost_mask + cost_dice
//   dot[b,n,m] = sum_l sigmoid(p[b,n,l]) * t[b,m,l]   (bf16 MFMA, fp32 acc)
//   sum_p[b,n] = sum_l sigmoid(p); sum_t[b,m] = sum_l t   (fp32 paths)
//   cost_class = -logits[b,n,label[b,m]]
//   cost_mask  = -(2*dot + L - sum_p - sum_t)/L
//   cost_dice  = 1 - (2*dot + 1)/(sum_p + sum_t + 1)
//
// LDS-free main, k-PERMUTED fragment loads: the reduction runs over all of L,
// so the MFMA k->lane mapping may be any permutation as long as A and B use
// the same one. Lane (kg,lr) takes its 8 k-values from float columns
// {4kg..4kg+4} u {16+4kg..16+4kg+4}: each float4 load instruction then covers
// full 64B lines (16 lines/instr, 100% utilization) instead of the natural
// A-layout's 32 half-lines/instr -- round-5 counters showed that pattern
// capped the memory path at 2.44 TB/s. pm loads and ws stores are
// non-temporal (read-once / write-once streams; keep L2 for gm reuse).
// NOTE: nontemporal builtins need ext_vector_type, not HIP float4 (round-6
// compile failure) -- all vector memory types here are fx4.

#define Lsz 65536
#define Bb 4
#define Nn 100
#define Mm 20
#define Cc 81
#define NP 112                  // padded N stride in ws dot region
#define SP_OFF (20 * NP)        // 2240: sum_p region
#define ST_OFF (20 * NP + NP)   // 2352: sum_t region
#define Pp (20 * NP + NP + 32)  // 2384 floats per (b,slot)
#define KBW 512                 // split-K slots per batch -> 2048 blocks, 8/CU
#define RL (Lsz / KBW)          // 128 l-values per block
#define GRP 16                  // reduction groups
#define SPG (KBW / GRP)         // 32 slots per group
#define JC 4                    // j-chunks in hung_red

typedef short bf16x8 __attribute__((ext_vector_type(8)));
typedef float fx4 __attribute__((ext_vector_type(4)));

__device__ __forceinline__ float sigmoid_fast(float x) {
    float e = __builtin_amdgcn_exp2f(x * -1.44269504088896340736f);
    return __builtin_amdgcn_rcpf(1.0f + e);
}

__device__ __forceinline__ ushort bf16rne(float f) {
    union { float f; unsigned u; } v; v.f = f;
    unsigned u = v.u;
    u += 0x7fffu + ((u >> 16) & 1u);
    return (ushort)(u >> 16);
}

__device__ __forceinline__ bf16x8 pack2x4(fx4 lo, fx4 hi) {
    bf16x8 r;
    r[0] = (short)bf16rne(lo.x); r[1] = (short)bf16rne(lo.y);
    r[2] = (short)bf16rne(lo.z); r[3] = (short)bf16rne(lo.w);
    r[4] = (short)bf16rne(hi.x); r[5] = (short)bf16rne(hi.y);
    r[6] = (short)bf16rne(hi.z); r[7] = (short)bf16rne(hi.w);
    return r;
}

__device__ __forceinline__ fx4 ntload4(const float* p) {
    return __builtin_nontemporal_load((const fx4*)p);
}

__global__ __launch_bounds__(256, 8) void hung_main(
    const float* __restrict__ pm,   // (B,N,L)
    const float* __restrict__ gm,   // (B,M,L)
    float* __restrict__ ws)         // (B,KBW,Pp) partials
{
    const int tid  = threadIdx.x;
    const int slot = blockIdx.x;
    const int b    = blockIdx.y;
    const int lane = tid & 63;
    const int w    = tid >> 6;     // wave 0..3: owns n-tiles {2w, 2w+1}
    const int lr   = lane & 15;
    const int kg   = lane >> 4;

    const int  rA0  = 32 * w + lr;        // n row of a0 fragment
    const int  rA1  = 32 * w + 16 + lr;   // n row of a1 fragment
    const bool vA0  = rA0 < Nn;           // false only for w==3, lr>=4
    const bool wlt3 = (w < 3);            // a1 tile exists
    const bool vB1  = (16 + lr) < Mm;     // lr < 4

    // permuted k-mapping: lane's two 16B chunks at float cols 4kg and 16+4kg
    const int l0 = slot * RL + 4 * kg;
    // clamp invalid rows to row 0: reads stay in-bounds, results discarded
    // at store time (store guards are the source of truth).
    const float* pA0 = pm + ((size_t)b * Nn + (vA0 ? rA0 : 0)) * Lsz + l0;
    const float* pA1 = pm + ((size_t)b * Nn + (wlt3 ? rA1 : 0)) * Lsz + l0;
    const float* pB0 = gm + ((size_t)b * Mm + lr) * Lsz + l0;
    const float* pB1 = gm + ((size_t)b * Mm + (vB1 ? 16 + lr : 0)) * Lsz + l0;

    fx4 acc00 = {0.f, 0.f, 0.f, 0.f};
    fx4 acc01 = {0.f, 0.f, 0.f, 0.f};
    fx4 acc10 = {0.f, 0.f, 0.f, 0.f};
    fx4 acc11 = {0.f, 0.f, 0.f, 0.f};
    float spA = 0.f, spB = 0.f, st0 = 0.f, st1 = 0.f;

    #pragma unroll 2
    for (int kk = 0; kk < RL / 32; ++kk) {
        const int o = kk * 32;
        // each instruction: 4 kg-lanes x 16B tile one full 64B line per row
        fx4 a0l = ntload4(pA0 + o), a0h = ntload4(pA0 + o + 16);
        fx4 b0l = *(const fx4*)(pB0 + o), b0h = *(const fx4*)(pB0 + o + 16);
        fx4 b1l = *(const fx4*)(pB1 + o), b1h = *(const fx4*)(pB1 + o + 16);

        float s0 = sigmoid_fast(a0l.x), s1 = sigmoid_fast(a0l.y);
        float s2 = sigmoid_fast(a0l.z), s3 = sigmoid_fast(a0l.w);
        float s4 = sigmoid_fast(a0h.x), s5 = sigmoid_fast(a0h.y);
        float s6 = sigmoid_fast(a0h.z), s7 = sigmoid_fast(a0h.w);
        spA += ((s0 + s1) + (s2 + s3)) + ((s4 + s5) + (s6 + s7));
        fx4 sa0l = {s0, s1, s2, s3}, sa0h = {s4, s5, s6, s7};
        bf16x8 fa0 = pack2x4(sa0l, sa0h);
        bf16x8 fb0 = pack2x4(b0l, b0h);
        bf16x8 fb1 = pack2x4(b1l, b1h);

        if (w == 0) {  // count each t element once per block
            st0 += ((b0l.x + b0l.y) + (b0l.z + b0l.w)) + ((b0h.x + b0h.y) + (b0h.z + b0h.w));
            st1 += ((b1l.x + b1l.y) + (b1l.z + b1l.w)) + ((b1h.x + b1h.y) + (b1h.z + b1h.w));
        }

        acc00 = __builtin_amdgcn_mfma_f32_16x16x32_bf16(fa0, fb0, acc00, 0, 0, 0);
        acc01 = __builtin_amdgcn_mfma_f32_16x16x32_bf16(fa0, fb1, acc01, 0, 0, 0);

        if (wlt3) {
            fx4 a1l = ntload4(pA1 + o), a1h = ntload4(pA1 + o + 16);
            float t0 = sigmoid_fast(a1l.x), t1 = sigmoid_fast(a1l.y);
            float t2 = sigmoid_fast(a1l.z), t3 = sigmoid_fast(a1l.w);
            float t4 = sigmoid_fast(a1h.x), t5 = sigmoid_fast(a1h.y);
            float t6 = sigmoid_fast(a1h.z), t7 = sigmoid_fast(a1h.w);
            spB += ((t0 + t1) + (t2 + t3)) + ((t4 + t5) + (t6 + t7));
            fx4 sa1l = {t0, t1, t2, t3}, sa1h = {t4, t5, t6, t7};
            bf16x8 fa1 = pack2x4(sa1l, sa1h);
            acc10 = __builtin_amdgcn_mfma_f32_16x16x32_bf16(fa1, fb0, acc10, 0, 0, 0);
            acc11 = __builtin_amdgcn_mfma_f32_16x16x32_bf16(fa1, fb1, acc11, 0, 0, 0);
        }
    }

    // reduce row-sums across the 4 kg lane-groups (lanes lr, 16+lr, 32+lr, 48+lr)
    spA += __shfl_xor(spA, 16, 64); spA += __shfl_xor(spA, 32, 64);
    spB += __shfl_xor(spB, 16, 64); spB += __shfl_xor(spB, 32, 64);
    st0 += __shfl_xor(st0, 16, 64); st0 += __shfl_xor(st0, 32, 64);
    st1 += __shfl_xor(st1, 16, 64); st1 += __shfl_xor(st1, 32, 64);

    float* wsb = ws + (size_t)(b * KBW + slot) * Pp;
    if (lane < 16) {  // kg==0, lr==lane
        if (vA0)  __builtin_nontemporal_store(spA, &wsb[SP_OFF + rA0]);
        if (wlt3) __builtin_nontemporal_store(spB, &wsb[SP_OFF + rA1]);
        if (w == 0) {
            __builtin_nontemporal_store(st0, &wsb[ST_OFF + lr]);
            if (lr < 4) __builtin_nontemporal_store(st1, &wsb[ST_OFF + 16 + lr]);
        }
    }

    // dot partials: C/D layout col=lane&15 (m), row=kg*4+e (n-local); each
    // acc fx4 covers 4 consecutive n -> 16B stores (wave covers full lines).
    const int nb = 32 * w + kg * 4;
    if (nb < Nn) {
        __builtin_nontemporal_store(acc00, (fx4*)&wsb[lr * NP + nb]);
        if (lr < 4)
            __builtin_nontemporal_store(acc01, (fx4*)&wsb[(16 + lr) * NP + nb]);
    }
    if (wlt3) {
        __builtin_nontemporal_store(acc10, (fx4*)&wsb[lr * NP + nb + 16]);
        if (lr < 4)
            __builtin_nontemporal_store(acc11, (fx4*)&wsb[(16 + lr) * NP + nb + 16]);
    }
}

// Stage 1: reduce 512 slots -> 16 groups of 32, coalesced, 256 blocks.
__global__ __launch_bounds__(256) void hung_red(
    const float* __restrict__ ws, float* __restrict__ ws2)
{
    const int g  = blockIdx.x;   // 0..GRP-1
    const int b  = blockIdx.y;   // 0..Bb-1
    const int jc = blockIdx.z;   // 0..JC-1
    const float* base = ws + ((size_t)b * KBW + (size_t)g * SPG) * Pp;
    float* outb = ws2 + ((size_t)b * GRP + g) * Pp;
    for (int j = jc * 256 + threadIdx.x; j < Pp; j += 256 * JC) {
        float s = 0.f;
        #pragma unroll 8
        for (int k = 0; k < SPG; ++k)
            s += __builtin_nontemporal_load(&base[(size_t)k * Pp + j]);
        outb[j] = s;
    }
}

__global__ __launch_bounds__(256) void hung_fin(
    const float* __restrict__ ws2,
    const float* __restrict__ logits,   // (B,N,C)
    const int*   __restrict__ labels,   // (B,M)
    float* __restrict__ out)            // (B,N,M)
{
    int t = blockIdx.x * 256 + threadIdx.x;
    if (t >= Bb * Nn * Mm) return;
    int b = t / (Nn * Mm);
    int r = t % (Nn * Mm);
    int m = r / Nn;       // n fast-varying -> coalesced ws2 reads
    int n = r % Nn;

    const float* p = ws2 + (size_t)b * GRP * Pp;
    float dot = 0.f, sp = 0.f, st = 0.f;
    #pragma unroll
    for (int g = 0; g < GRP; ++g) {
        dot += p[m * NP + n];
        sp  += p[SP_OFF + n];
        st  += p[ST_OFF + m];
        p += Pp;
    }

    int lab = labels[b * Mm + m];
    float cc = -logits[(size_t)(b * Nn + n) * Cc + lab];
    const float invL = 1.0f / (float)Lsz;
    float cm = -(2.f * dot + (float)Lsz - sp - st) * invL;
    float cd = 1.f - (2.f * dot + 1.f) / (sp + st + 1.f);
    out[(size_t)b * (Nn * Mm) + n * Mm + m] = cc + cm + cd;
}

extern "C" void kernel_launch(void* const* d_in, const int* in_sizes, int n_in,
                              void* d_out, int out_size, void* d_ws, size_t ws_size,
                              hipStream_t stream) {
    const float* logits = (const float*)d_in[0];
    const float* pmasks = (const float*)d_in[1];
    const int*   labels = (const int*)d_in[2];
    const float* gmasks = (const float*)d_in[3];
    float* out = (float*)d_out;
    float* ws  = (float*)d_ws;                         // Bb*KBW*Pp = 19.5 MB
    float* ws2 = ws + (size_t)Bb * KBW * Pp;           // Bb*GRP*Pp = 610 KB

    hung_main<<<dim3(KBW, Bb), 256, 0, stream>>>(pmasks, gmasks, ws);
    hung_red<<<dim3(GRP, Bb, JC), 256, 0, stream>>>(ws, ws2);
    hung_fin<<<(Bb * Nn * Mm + 255) / 256, 256, 0, stream>>>(ws2, logits, labels, out);
}